// Round 1
// baseline (6005.897 us; speedup 1.0000x reference)
//
#include <hip/hip_runtime.h>
#include <stdint.h>

// ---------------------------------------------------------------------------
// LSTM forward, T=2048 B=64 I=H=512.
// Phase 1: Xg = X @ [W_xf|W_xi|W_xo|W_xc]  (bf16 MFMA GEMM, m97-style tile)
// Phase 2: persistent recurrence kernel, 4 batch-groups x 64 hidden-groups,
//          W_h slices stationary in LDS, flag-based agent-scope sync.
// ---------------------------------------------------------------------------

typedef __attribute__((ext_vector_type(8))) short short8;
typedef __attribute__((ext_vector_type(4))) float f32x4;

#define T_STEPS 2048
#define GB 4
#define GH 64
#define FSTRIDE 16  // ints between flags (64B cacheline spacing)

__device__ __forceinline__ unsigned short f2bf(float f) {
  unsigned int x = __float_as_uint(f);
  x += 0x7fffu + ((x >> 16) & 1u);   // RNE
  return (unsigned short)(x >> 16);
}
__device__ __forceinline__ float bf2f(unsigned short u) {
  return __uint_as_float(((unsigned int)u) << 16);
}
// async global->LDS, 16B per lane; lds base must be wave-uniform.
__device__ __forceinline__ void gl2lds16(const void* g, void* lds) {
  __builtin_amdgcn_global_load_lds(
      (const __attribute__((address_space(1))) void*)(uintptr_t)g,
      (__attribute__((address_space(3))) void*)(unsigned int)(uintptr_t)lds,
      16, 0, 0);
}

// --------------------------- phase 0: casts/packs ---------------------------

__global__ __launch_bounds__(256) void cast_x_kernel(
    const float* __restrict__ X, unsigned short* __restrict__ Xb) {
  long long i = ((long long)blockIdx.x * 256 + threadIdx.x) * 8;
  float4 a = *(const float4*)(X + i);
  float4 b = *(const float4*)(X + i + 4);
  union { short8 v; unsigned short u[8]; } o;
  o.u[0] = f2bf(a.x); o.u[1] = f2bf(a.y); o.u[2] = f2bf(a.z); o.u[3] = f2bf(a.w);
  o.u[4] = f2bf(b.x); o.u[5] = f2bf(b.y); o.u[6] = f2bf(b.z); o.u[7] = f2bf(b.w);
  *(short8*)(Xb + i) = o.v;
}

// Wt[n][k] = W_gate(n/512)[k][n%512]  (transposed, bf16)  n in [0,2048)
__global__ __launch_bounds__(256) void pack_w_kernel(
    const float* __restrict__ Wf, const float* __restrict__ Wi,
    const float* __restrict__ Wo, const float* __restrict__ Wc,
    unsigned short* __restrict__ Wt) {
  int n = blockIdx.x;
  int g = n >> 9, h = n & 511;
  const float* W = (g == 0) ? Wf : (g == 1) ? Wi : (g == 2) ? Wo : Wc;
  for (int k = threadIdx.x; k < 512; k += 256)
    Wt[(size_t)n * 512 + k] = f2bf(W[(size_t)k * 512 + h]);
}

__global__ __launch_bounds__(256) void init_kernel(unsigned short* hbuf, int* flags) {
  int i = blockIdx.x * 256 + threadIdx.x;
  if (i < 2 * 64 * 512) hbuf[i] = 0;
  if (i < GB * GH * FSTRIDE) flags[i] = 0;
}

// --------------------------- phase 1: input GEMM ---------------------------
// A [131072,512] bf16 row-major; Bt [2048,512] bf16 (B transposed);
// C [131072,2048] bf16. 128x128 tile, BK=64, 4 waves in 2x2, 4x4 MFMA each.
__global__ __launch_bounds__(256) void gemm_xg_kernel(
    const unsigned short* __restrict__ A, const unsigned short* __restrict__ Bt,
    unsigned short* __restrict__ C) {
  __shared__ unsigned short As[128 * 64];
  __shared__ unsigned short Bs[128 * 64];
  const int tid = threadIdx.x;
  const int lane = tid & 63, wave = tid >> 6;
  const int bm = blockIdx.x, bn = blockIdx.y;
  const int wm = (wave & 1) * 64, wn = (wave >> 1) * 64;

  f32x4 acc[4][4];
#pragma unroll
  for (int i = 0; i < 4; ++i)
#pragma unroll
    for (int j = 0; j < 4; ++j) acc[i][j] = (f32x4){0.f, 0.f, 0.f, 0.f};

  for (int kt = 0; kt < 512; kt += 64) {
    __syncthreads();  // previous compute done before LDS overwrite
#pragma unroll
    for (int r = 0; r < 4; ++r) {
      int chunk = r * 256 + tid;          // [0,1024): row=chunk>>3, c8=chunk&7
      int row = chunk >> 3, c8 = chunk & 7;
      gl2lds16(A + ((size_t)(bm * 128 + row) * 512 + kt + c8 * 8),
               (void*)(As + (size_t)(r * 256 + wave * 64) * 8));
      gl2lds16(Bt + ((size_t)(bn * 128 + row) * 512 + kt + c8 * 8),
               (void*)(Bs + (size_t)(r * 256 + wave * 64) * 8));
    }
    __syncthreads();  // staging complete (vmcnt drained by barrier)
#pragma unroll
    for (int kc = 0; kc < 64; kc += 32) {
      const int ko = kc + (lane >> 4) * 8;
      short8 av[4], bv[4];
#pragma unroll
      for (int mt = 0; mt < 4; ++mt)
        av[mt] = *(const short8*)(As + (wm + mt * 16 + (lane & 15)) * 64 + ko);
#pragma unroll
      for (int nt = 0; nt < 4; ++nt)
        bv[nt] = *(const short8*)(Bs + (wn + nt * 16 + (lane & 15)) * 64 + ko);
#pragma unroll
      for (int mt = 0; mt < 4; ++mt)
#pragma unroll
        for (int nt = 0; nt < 4; ++nt)
          acc[mt][nt] = __builtin_amdgcn_mfma_f32_16x16x32_bf16(
              av[mt], bv[nt], acc[mt][nt], 0, 0, 0);
    }
  }
  const int q = lane >> 4, cidx = lane & 15;
#pragma unroll
  for (int mt = 0; mt < 4; ++mt)
#pragma unroll
    for (int nt = 0; nt < 4; ++nt)
#pragma unroll
      for (int r = 0; r < 4; ++r) {
        int row = wm + mt * 16 + q * 4 + r;  // C/D: col=lane&15, row=quad*4+reg
        int col = wn + nt * 16 + cidx;
        C[(size_t)(bm * 128 + row) * 2048 + bn * 128 + col] = f2bf(acc[mt][nt][r]);
      }
}

// --------------------------- phase 2: recurrence ---------------------------
// grid 256 = GB(4) x GH(64). WG (gb,gh): batch slice gb*16..+16, hidden slice
// gh*8..+8 (-> 32 W_h columns: 4 gates x 8). W_h slice transposed in LDS.
__global__ __launch_bounds__(256) void lstm_rec_kernel(
    const unsigned short* __restrict__ Xg,   // [T*64][2048] bf16
    const unsigned short* __restrict__ Wht,  // [2048][512] bf16 (row n = g*512+h)
    const float* __restrict__ b_f, const float* __restrict__ b_i,
    const float* __restrict__ b_o, const float* __restrict__ b_c,
    float* __restrict__ out, unsigned short* hbuf, int* flags) {
  const int tid = threadIdx.x;
  const int lane = tid & 63, wave = tid >> 6;
  const int gb = blockIdx.x >> 6;
  const int gh = blockIdx.x & 63;

  __shared__ unsigned short Wl[32][520];  // [col=g*8+j][k], +8 pad: 2-way bank max
  __shared__ float Cred[4][16][33];       // per-wave partial C, padded

  for (int idx = tid; idx < 32 * 64; idx += 256) {
    int cc = idx >> 6, k8 = idx & 63;
    int n = (cc >> 3) * 512 + gh * 8 + (cc & 7);
    short8 v = *(const short8*)(Wht + (size_t)n * 512 + k8 * 8);
    *(short8*)(&Wl[cc][k8 * 8]) = v;
  }

  float creg = 0.f;
  float bias0 = 0.f, bias1 = 0.f, bias2 = 0.f, bias3 = 0.f;
  int bb = 0, jj = 0;
  if (tid < 128) {
    bb = tid >> 3; jj = tid & 7;
    int col = gh * 8 + jj;
    bias0 = b_f[col]; bias1 = b_i[col]; bias2 = b_o[col]; bias3 = b_c[col];
  }
  __syncthreads();

  const int myflag = (gb * GH + gh) * FSTRIDE;

  for (int t = 0; t < T_STEPS; ++t) {
    // Xg loads issued early: independent of h_t, latency hidden under spin+MFMA
    float xg0 = 0.f, xg1 = 0.f, xg2 = 0.f, xg3 = 0.f;
    if (tid < 128) {
      const unsigned short* xr =
          Xg + ((size_t)t * 64 + gb * 16 + bb) * 2048 + gh * 8 + jj;
      xg0 = bf2f(xr[0]); xg1 = bf2f(xr[512]); xg2 = bf2f(xr[1024]); xg3 = bf2f(xr[1536]);
    }
    if (t > 0) {
      if (tid < GH) {
        const int* fp = flags + (gb * GH + tid) * FSTRIDE;
        while (__hip_atomic_load(fp, __ATOMIC_RELAXED, __HIP_MEMORY_SCOPE_AGENT) < t)
          __builtin_amdgcn_s_sleep(1);
      }
      __syncthreads();
      __builtin_amdgcn_fence(__ATOMIC_ACQUIRE, "workgroup");  // compiler ordering
    }
    // MFMA partials: wave handles k in [wave*128, wave*128+128)
    const unsigned short* hrow =
        hbuf + ((size_t)(t & 1) * 64 * 512) + (size_t)gb * 16 * 512;
    f32x4 acc0 = {0.f, 0.f, 0.f, 0.f}, acc1 = {0.f, 0.f, 0.f, 0.f};
    const int m = lane & 15, quad = lane >> 4;
#pragma unroll
    for (int kc = 0; kc < 128; kc += 32) {
      int k = wave * 128 + kc + quad * 8;
      const unsigned long long* ap =
          (const unsigned long long*)(hrow + (size_t)m * 512 + k);
      union { short8 v; unsigned long long q[2]; } au;
      au.q[0] = __hip_atomic_load(ap, __ATOMIC_RELAXED, __HIP_MEMORY_SCOPE_AGENT);
      au.q[1] = __hip_atomic_load(ap + 1, __ATOMIC_RELAXED, __HIP_MEMORY_SCOPE_AGENT);
      short8 bfr0 = *(const short8*)(&Wl[m][k]);
      short8 bfr1 = *(const short8*)(&Wl[16 + m][k]);
      acc0 = __builtin_amdgcn_mfma_f32_16x16x32_bf16(au.v, bfr0, acc0, 0, 0, 0);
      acc1 = __builtin_amdgcn_mfma_f32_16x16x32_bf16(au.v, bfr1, acc1, 0, 0, 0);
    }
#pragma unroll
    for (int r = 0; r < 4; ++r) {
      Cred[wave][quad * 4 + r][m] = acc0[r];
      Cred[wave][quad * 4 + r][16 + m] = acc1[r];
    }
    __syncthreads();
    if (tid < 128) {
      float gf = Cred[0][bb][jj] + Cred[1][bb][jj] + Cred[2][bb][jj] + Cred[3][bb][jj];
      float gi = Cred[0][bb][8+jj] + Cred[1][bb][8+jj] + Cred[2][bb][8+jj] + Cred[3][bb][8+jj];
      float go = Cred[0][bb][16+jj] + Cred[1][bb][16+jj] + Cred[2][bb][16+jj] + Cred[3][bb][16+jj];
      float gc = Cred[0][bb][24+jj] + Cred[1][bb][24+jj] + Cred[2][bb][24+jj] + Cred[3][bb][24+jj];
      gf += bias0 + xg0; gi += bias1 + xg1; go += bias2 + xg2; gc += bias3 + xg3;
      float f  = 1.f / (1.f + __expf(-gf));
      float ii = 1.f / (1.f + __expf(-gi));
      float oo = 1.f / (1.f + __expf(-go));
      float ch = 1.f - 2.f / (1.f + __expf(2.f * gc));   // tanh
      creg = f * creg + ii * ch;
      float tc = 1.f - 2.f / (1.f + __expf(2.f * creg));
      float h = oo * tc;
      size_t orow = ((size_t)t * 64 + gb * 16 + bb) * 512 + gh * 8 + jj;
      out[orow] = h;
      // agent-scope (sc1) store: bypasses non-coherent L2, lands at L3
      __hip_atomic_store(hbuf + ((size_t)((t + 1) & 1) * 64 * 512) +
                             (size_t)(gb * 16 + bb) * 512 + gh * 8 + jj,
                         f2bf(h), __ATOMIC_RELAXED, __HIP_MEMORY_SCOPE_AGENT);
      if (t == T_STEPS - 1) {
        size_t base = (size_t)T_STEPS * 64 * 512;
        out[base + (size_t)(gb * 16 + bb) * 512 + gh * 8 + jj] = h;
        out[base + 64 * 512 + (size_t)(gb * 16 + bb) * 512 + gh * 8 + jj] = creg;
      }
    }
    __syncthreads();  // barrier drains each wave's vmcnt -> h stores visible
    __builtin_amdgcn_fence(__ATOMIC_RELEASE, "workgroup");  // compiler ordering
    if (tid == 0)
      __hip_atomic_store(flags + myflag, t + 1, __ATOMIC_RELAXED,
                         __HIP_MEMORY_SCOPE_AGENT);
  }
}

// ------------------------------- launch ------------------------------------

extern "C" void kernel_launch(void* const* d_in, const int* in_sizes, int n_in,
                              void* d_out, int out_size, void* d_ws, size_t ws_size,
                              hipStream_t stream) {
  const float* X    = (const float*)d_in[0];
  const float* W_xf = (const float*)d_in[1];
  const float* W_hf = (const float*)d_in[2];
  const float* b_f  = (const float*)d_in[3];
  const float* W_xi = (const float*)d_in[4];
  const float* W_hi = (const float*)d_in[5];
  const float* b_i  = (const float*)d_in[6];
  const float* W_xo = (const float*)d_in[7];
  const float* W_ho = (const float*)d_in[8];
  const float* b_o  = (const float*)d_in[9];
  const float* W_xc = (const float*)d_in[10];
  const float* W_hc = (const float*)d_in[11];
  const float* b_c  = (const float*)d_in[12];
  float* out = (float*)d_out;

  char* ws = (char*)d_ws;
  unsigned short* Xb   = (unsigned short*)(ws + 0LL);           // 134,217,728 B
  unsigned short* Xg   = (unsigned short*)(ws + 134217728LL);   // 536,870,912 B
  unsigned short* Wxt  = (unsigned short*)(ws + 671088640LL);   //   2,097,152 B
  unsigned short* Wht  = (unsigned short*)(ws + 673185792LL);   //   2,097,152 B
  unsigned short* hbuf = (unsigned short*)(ws + 675282944LL);   //     131,072 B
  int* flags           = (int*)(ws + 675414016LL);              //      16,384 B

  cast_x_kernel<<<dim3(32768), dim3(256), 0, stream>>>(X, Xb);
  pack_w_kernel<<<dim3(2048), dim3(256), 0, stream>>>(W_xf, W_xi, W_xo, W_xc, Wxt);
  pack_w_kernel<<<dim3(2048), dim3(256), 0, stream>>>(W_hf, W_hi, W_ho, W_hc, Wht);
  init_kernel<<<dim3(256), dim3(256), 0, stream>>>(hbuf, flags);
  gemm_xg_kernel<<<dim3(1024, 16), dim3(256), 0, stream>>>(Xb, Wxt, Xg);
  lstm_rec_kernel<<<dim3(256), dim3(256), 0, stream>>>(Xg, Wht, b_f, b_i, b_o, b_c,
                                                       out, hbuf, flags);
}